// Round 8
// baseline (452.989 us; speedup 1.0000x reference)
//
#include <hip/hip_runtime.h>
#include <hip/hip_bf16.h>
#include <hip/hip_cooperative_groups.h>

namespace cg = cooperative_groups;

#define FIN 256
#define HID 64
#define EMB 2
#define BKB 9            // bucket = dst >> 9 (512 nodes per bucket)
#define BKSZ 512
#define MAXBK 256        // supports N <= 131072
#define NBLK 256         // blocks for binning passes

typedef __bf16 bf16x8 __attribute__((ext_vector_type(8)));
typedef float  f32x16 __attribute__((ext_vector_type(16)));

// ---- bf16 helpers (RNE) ----
static __device__ __forceinline__ unsigned short f2bf(float f) {
    union { float f; unsigned int u; } v; v.f = f;
    unsigned int u = v.u;
    unsigned int r = (u + 0x7fffu + ((u >> 16) & 1u)) >> 16;
    return (unsigned short)r;
}
static __device__ __forceinline__ float bf2f(unsigned short h) {
    union { unsigned int u; float f; } v; v.u = ((unsigned int)h) << 16;
    return v.f;
}

// ---------------------------------------------------------------------------
// Fused CSR build (cooperative, NBLK blocks x 256):
//   P1 coarse hist -> P2 per-bucket scan -> P3 total scan + zero accum/done
//   -> P4 bucket-ordered scatter -> P5 per-bucket fine build (dinv/rowptr/csr)
__global__ __launch_bounds__(256) void build_all_kernel(
        const int* __restrict__ src, const int* __restrict__ dst,
        int* __restrict__ counts, int* __restrict__ btot,
        int* __restrict__ bucketBase, unsigned* __restrict__ ebuf,
        int* __restrict__ rowptr, float* __restrict__ dinv, int* __restrict__ csr,
        float* __restrict__ sums, int* __restrict__ done,
        int E, int chunk, int NBK, int N, int nzero) {
    cg::grid_group grid = cg::this_grid();
    __shared__ int lds[1280];   // 5 KB, re-purposed per phase
    const int blk = blockIdx.x, tid = threadIdx.x;

    // ---- Phase 1: per-block coarse histogram of dst>>BKB ----
    {
        int* hist = lds;
        for (int b = tid; b < NBK; b += 256) hist[b] = 0;
        __syncthreads();
        int e0 = blk * chunk, e1 = min(e0 + chunk, E);
        for (int i = e0 + tid; i < e1; i += 256) atomicAdd(&hist[dst[i] >> BKB], 1);
        __syncthreads();
        for (int b = tid; b < NBK; b += 256) counts[b * NBLK + blk] = hist[b];
    }
    grid.sync();

    // ---- Phase 2: per-bucket exclusive scan of its per-block counts ----
    if (blk < NBK) {
        int* s = lds;
        int v = counts[blk * NBLK + tid];
        s[tid] = v;
        __syncthreads();
        for (int off = 1; off < 256; off <<= 1) {
            int t = (tid >= off) ? s[tid - off] : 0;
            __syncthreads();
            s[tid] += t;
            __syncthreads();
        }
        counts[blk * NBLK + tid] = s[tid] - v;
        if (tid == 255) btot[blk] = s[255];
    }
    grid.sync();

    // ---- Phase 3: scan bucket totals; zero pool accumulators + done flag ----
    if (blk == 0) {
        int* s = lds;
        int v = (tid < NBK) ? btot[tid] : 0;
        s[tid] = v;
        __syncthreads();
        for (int off = 1; off < 256; off <<= 1) {
            int t = (tid >= off) ? s[tid - off] : 0;
            __syncthreads();
            s[tid] += t;
            __syncthreads();
        }
        if (tid < NBK) bucketBase[tid] = s[tid] - v;
        if (tid == NBK - 1) bucketBase[NBK] = s[tid];
        for (int i = tid; i < nzero; i += 256) sums[i] = 0.f;
        if (tid == 0) *done = 0;
    }
    grid.sync();

    // ---- Phase 4: scatter packed (src<<9 | dst&511) into bucket runs ----
    {
        int* cur = lds;
        for (int b = tid; b < NBK; b += 256)
            cur[b] = bucketBase[b] + counts[b * NBLK + blk];
        __syncthreads();
        int e0 = blk * chunk, e1 = min(e0 + chunk, E);
        for (int i = e0 + tid; i < e1; i += 256) {
            int s = src[i], d = dst[i];
            int b = d >> BKB;
            int pos = atomicAdd(&cur[b], 1);
            ebuf[pos] = ((unsigned)s << BKB) | (unsigned)(d & (BKSZ - 1));
        }
    }
    grid.sync();

    // ---- Phase 5: per-bucket fine build (degree/dinv/rowptr + CSR scatter) ----
    if (blk < NBK) {
        int* hist  = lds;         // 512 ints
        int* scanb = lds + 512;   // 256 ints
        int* cur   = lds + 768;   // 512 ints
        const int r0 = bucketBase[blk];
        const int r1 = bucketBase[blk + 1];
        const int nb0 = blk * BKSZ;

        hist[tid] = 0; hist[tid + 256] = 0;
        __syncthreads();
        for (int i = r0 + tid; i < r1; i += 256)
            atomicAdd(&hist[ebuf[i] & (BKSZ - 1u)], 1);
        __syncthreads();

        int h0 = hist[2 * tid], h1 = hist[2 * tid + 1];
        if (nb0 + 2 * tid < N)     dinv[nb0 + 2 * tid]     = rsqrtf((float)h0 + 1.f);
        if (nb0 + 2 * tid + 1 < N) dinv[nb0 + 2 * tid + 1] = rsqrtf((float)h1 + 1.f);
        scanb[tid] = h0 + h1;
        __syncthreads();
        for (int off = 1; off < 256; off <<= 1) {
            int t = (tid >= off) ? scanb[tid - off] : 0;
            __syncthreads();
            scanb[tid] += t;
            __syncthreads();
        }
        int base0 = scanb[tid] - (h0 + h1);
        int o0 = base0, o1 = base0 + h0;
        cur[2 * tid] = o0; cur[2 * tid + 1] = o1;
        if (nb0 + 2 * tid < N)     rowptr[nb0 + 2 * tid]     = r0 + o0;
        if (nb0 + 2 * tid + 1 < N) rowptr[nb0 + 2 * tid + 1] = r0 + o1;
        if (nb0 + BKSZ >= N && tid == 0) rowptr[N] = E;
        __syncthreads();
        for (int i = r0 + tid; i < r1; i += 256) {
            unsigned u = ebuf[i];
            int loc = (int)(u & (BKSZ - 1u));
            int p = atomicAdd(&cur[loc], 1);
            csr[r0 + p] = (int)(u >> BKB);
        }
    }
}

// ---------------------------------------------------------------------------
// h1' = dinv * (x @ W1) via MFMA (bf16 hi/lo split: xh*wh + xh*wl + xl*wh).
// Block = 64-node x 64-feat tile, 4 waves = four 32x32 quadrants. bf16 store.
__global__ __launch_bounds__(256) void gemm1_kernel(
        const float* __restrict__ x, const float* __restrict__ W,
        const float* __restrict__ dinv, unsigned short* __restrict__ h1b, int N) {
    __shared__ __align__(16) __bf16 A_hi[2 * 4 * 64 * 8];
    __shared__ __align__(16) __bf16 A_lo[2 * 4 * 64 * 8];
    __shared__ __align__(16) __bf16 B_hi[2 * 4 * 64 * 8];
    __shared__ __align__(16) __bf16 B_lo[2 * 4 * 64 * 8];

    const int tid = threadIdx.x;
    const int base = blockIdx.x * 64;
    const int w = tid >> 6;
    const int l = tid & 63;
    const int mg = w >> 1, ng = w & 1;

    f32x16 acc = {};

    const int r  = tid & 63;
    const int ks = tid >> 6;
    const int rl = r & 31, rh = r >> 5;

    for (int ch = 0; ch < 4; ++ch) {
        const int ck0 = ch * 64;
        __syncthreads();
        {
            int row = base + r;
            float f[16];
            if (row < N) {
                const float* xp = &x[(size_t)row * FIN + ck0 + ks * 16];
                float4 v0 = *(const float4*)(xp + 0);
                float4 v1 = *(const float4*)(xp + 4);
                float4 v2 = *(const float4*)(xp + 8);
                float4 v3 = *(const float4*)(xp + 12);
                f[0]=v0.x; f[1]=v0.y; f[2]=v0.z; f[3]=v0.w;
                f[4]=v1.x; f[5]=v1.y; f[6]=v1.z; f[7]=v1.w;
                f[8]=v2.x; f[9]=v2.y; f[10]=v2.z; f[11]=v2.w;
                f[12]=v3.x; f[13]=v3.y; f[14]=v3.z; f[15]=v3.w;
            } else {
                #pragma unroll
                for (int q = 0; q < 16; ++q) f[q] = 0.f;
            }
            bf16x8 ha, hb, la, lb;
            #pragma unroll
            for (int q = 0; q < 8; ++q) {
                __bf16 h0 = (__bf16)f[q];
                ha[q] = h0; la[q] = (__bf16)(f[q] - (float)h0);
                __bf16 h1v = (__bf16)f[q + 8];
                hb[q] = h1v; lb[q] = (__bf16)(f[q + 8] - (float)h1v);
            }
            int ra = ((rh * 4 + ks) * 64 + rl) * 8;
            int rb = ((rh * 4 + ks) * 64 + 32 + rl) * 8;
            *(bf16x8*)&A_hi[ra] = ha; *(bf16x8*)&A_hi[rb] = hb;
            *(bf16x8*)&A_lo[ra] = la; *(bf16x8*)&A_lo[rb] = lb;
        }
        {
            const float* wp = &W[(size_t)(ck0 + ks * 16) * HID + r];
            float f[16];
            #pragma unroll
            for (int q = 0; q < 16; ++q) f[q] = wp[q * HID];
            bf16x8 ha, hb, la, lb;
            #pragma unroll
            for (int q = 0; q < 8; ++q) {
                __bf16 h0 = (__bf16)f[q];
                ha[q] = h0; la[q] = (__bf16)(f[q] - (float)h0);
                __bf16 h1v = (__bf16)f[q + 8];
                hb[q] = h1v; lb[q] = (__bf16)(f[q + 8] - (float)h1v);
            }
            int ra = ((rh * 4 + ks) * 64 + rl) * 8;
            int rb = ((rh * 4 + ks) * 64 + 32 + rl) * 8;
            *(bf16x8*)&B_hi[ra] = ha; *(bf16x8*)&B_hi[rb] = hb;
            *(bf16x8*)&B_lo[ra] = la; *(bf16x8*)&B_lo[rb] = lb;
        }
        __syncthreads();

        #pragma unroll
        for (int s = 0; s < 4; ++s) {
            bf16x8 a_h = *(const bf16x8*)&A_hi[((mg * 4 + s) * 64 + l) * 8];
            bf16x8 a_l = *(const bf16x8*)&A_lo[((mg * 4 + s) * 64 + l) * 8];
            bf16x8 b_h = *(const bf16x8*)&B_hi[((ng * 4 + s) * 64 + l) * 8];
            bf16x8 b_l = *(const bf16x8*)&B_lo[((ng * 4 + s) * 64 + l) * 8];
            acc = __builtin_amdgcn_mfma_f32_32x32x16_bf16(a_h, b_h, acc, 0, 0, 0);
            acc = __builtin_amdgcn_mfma_f32_32x32x16_bf16(a_h, b_l, acc, 0, 0, 0);
            acc = __builtin_amdgcn_mfma_f32_32x32x16_bf16(a_l, b_h, acc, 0, 0, 0);
        }
    }

    const int col = l & 31;
    const int rbase = 4 * (l >> 5);
    #pragma unroll
    for (int reg = 0; reg < 16; ++reg) {
        int row = (reg & 3) + 8 * (reg >> 2) + rbase;
        int node = base + mg * 32 + row;
        if (node < N)
            h1b[(size_t)node * HID + ng * 32 + col] = f2bf(acc[reg] * dinv[node]);
    }
}

// ---------------------------------------------------------------------------
// Fused layer-1 CSR gather (pure sum of pre-scaled h1') + b1 + ReLU + (64->2).
// 4 nodes per wave: 16 lanes/node, lane = 4 feats (ushort4 gather).
__global__ __launch_bounds__(256) void agg1_layer2_kernel(
        const int* __restrict__ rowptr, const int* __restrict__ csr,
        const unsigned short* __restrict__ h1b,
        const float* __restrict__ dinv, const float* __restrict__ b1,
        const float* __restrict__ W2, float* __restrict__ h2, int N) {
    long t = (long)blockIdx.x * blockDim.x + threadIdx.x;
    int n = (int)(t >> 4);
    int li = threadIdx.x & 15;
    if (n >= N) return;
    const ushort4* h14 = (const ushort4*)h1b;

    float di = dinv[n];
    ushort4 sl = h14[(size_t)n * 16 + li];       // self term (h1' pre-scaled)
    float v0 = bf2f(sl.x), v1 = bf2f(sl.y);
    float v2 = bf2f(sl.z), v3 = bf2f(sl.w);

    int j0 = rowptr[n], j1 = rowptr[n + 1];
    int j = j0;
    for (; j + 3 < j1; j += 4) {
        int s0 = csr[j], s1 = csr[j + 1], s2 = csr[j + 2], s3 = csr[j + 3];
        ushort4 g0 = h14[(size_t)s0 * 16 + li];
        ushort4 g1 = h14[(size_t)s1 * 16 + li];
        ushort4 g2 = h14[(size_t)s2 * 16 + li];
        ushort4 g3 = h14[(size_t)s3 * 16 + li];
        v0 += bf2f(g0.x) + bf2f(g1.x) + bf2f(g2.x) + bf2f(g3.x);
        v1 += bf2f(g0.y) + bf2f(g1.y) + bf2f(g2.y) + bf2f(g3.y);
        v2 += bf2f(g0.z) + bf2f(g1.z) + bf2f(g2.z) + bf2f(g3.z);
        v3 += bf2f(g0.w) + bf2f(g1.w) + bf2f(g2.w) + bf2f(g3.w);
    }
    for (; j < j1; ++j) {
        int s = csr[j];
        ushort4 g = h14[(size_t)s * 16 + li];
        v0 += bf2f(g.x); v1 += bf2f(g.y); v2 += bf2f(g.z); v3 += bf2f(g.w);
    }

    const float4 b4 = *(const float4*)&b1[li * 4];
    v0 = fmaxf(di * v0 + b4.x, 0.f); v1 = fmaxf(di * v1 + b4.y, 0.f);
    v2 = fmaxf(di * v2 + b4.z, 0.f); v3 = fmaxf(di * v3 + b4.w, 0.f);

    const float4* W24 = (const float4*)W2;
    float4 wa = W24[li * 2], wb = W24[li * 2 + 1];
    float r0 = v0 * wa.x + v1 * wa.z + v2 * wb.x + v3 * wb.z;
    float r1 = v0 * wa.y + v1 * wa.w + v2 * wb.y + v3 * wb.w;
    #pragma unroll
    for (int off = 1; off < 16; off <<= 1) {
        r0 += __shfl_xor(r0, off);
        r1 += __shfl_xor(r1, off);
    }
    if (li == 0) *(float2*)&h2[(size_t)n * EMB] = make_float2(r0 * di, r1 * di);  // h2' = dinv*h2
}

// ---------------------------------------------------------------------------
// Fused layer-2 CSR gather (pure sum of h2') + b2 + global mean pool
// + last-block finalize (sums/cnt -> out).
__global__ __launch_bounds__(256) void agg2_pool_final_kernel(
        const int* __restrict__ rowptr, const int* __restrict__ csr,
        const float* __restrict__ h2,
        const float* __restrict__ dinv, const float* __restrict__ b2,
        const int* __restrict__ batch,
        float* __restrict__ sums, float* __restrict__ cntf,
        float* __restrict__ out, int* __restrict__ done, int N, int G) {
    int n = blockIdx.x * blockDim.x + threadIdx.x;
    int lane = threadIdx.x & 63;
    const float2* h2v = (const float2*)h2;
    float v0 = 0.f, v1 = 0.f, c = 0.f;
    int g = -1;
    if (n < N) {
        float di = dinv[n];
        float2 hs = h2v[n];
        v0 = hs.x; v1 = hs.y;
        int j0 = rowptr[n], j1 = rowptr[n + 1];
        int j = j0;
        for (; j + 3 < j1; j += 4) {
            int s0 = csr[j], s1 = csr[j + 1], s2 = csr[j + 2], s3 = csr[j + 3];
            float2 a = h2v[s0], b = h2v[s1], cc = h2v[s2], d = h2v[s3];
            v0 += a.x + b.x + cc.x + d.x;
            v1 += a.y + b.y + cc.y + d.y;
        }
        for (; j < j1; ++j) {
            float2 hv = h2v[csr[j]];
            v0 += hv.x; v1 += hv.y;
        }
        v0 = di * v0 + b2[0];
        v1 = di * v1 + b2[1];
        g = batch[n];
        c = 1.f;
    }
    #pragma unroll
    for (int off = 1; off < 64; off <<= 1) {
        int gg = __shfl_up(g, off);
        float t0 = __shfl_up(v0, off);
        float t1 = __shfl_up(v1, off);
        float tc = __shfl_up(c, off);
        if (lane >= off && gg == g) { v0 += t0; v1 += t1; c += tc; }
    }
    int gn = __shfl_down(g, 1);
    if (g >= 0 && (lane == 63 || gn != g)) {
        atomicAdd(&sums[g * EMB + 0], v0);
        atomicAdd(&sums[g * EMB + 1], v1);
        atomicAdd(&cntf[g], c);
    }

    // last-finished block finalizes out = sums / max(cnt,1)
    __shared__ int isLast;
    __threadfence();
    if (threadIdx.x == 0) {
        int v = atomicAdd(done, 1);
        isLast = (v == (int)gridDim.x - 1);
    }
    __syncthreads();
    if (isLast) {
        __threadfence();
        const volatile float* vs = sums;
        const volatile float* vc = cntf;
        for (int gg = threadIdx.x; gg < G; gg += blockDim.x) {
            float cc = vc[gg];
            cc = fmaxf(cc, 1.0f);
            out[gg * EMB + 0] = vs[gg * EMB + 0] / cc;
            out[gg * EMB + 1] = vs[gg * EMB + 1] / cc;
        }
    }
}

// ---------------------------------------------------------------------------
extern "C" void kernel_launch(void* const* d_in, const int* in_sizes, int n_in,
                              void* d_out, int out_size, void* d_ws, size_t ws_size,
                              hipStream_t stream) {
    const float* x     = (const float*)d_in[0];
    const int*   ei    = (const int*)d_in[1];
    const int*   batch = (const int*)d_in[2];
    const float* W1    = (const float*)d_in[3];
    const float* b1    = (const float*)d_in[4];
    const float* W2    = (const float*)d_in[5];
    const float* b2    = (const float*)d_in[6];
    float* out = (float*)d_out;

    const int N = in_sizes[0] / FIN;   // 100000
    const int E = in_sizes[1] / 2;     // 1600000
    const int G = out_size / EMB;      // 512
    const int* src = ei;
    const int* dst = ei + E;

    const int NBK = (N + BKSZ - 1) / BKSZ;   // 196 coarse buckets
    const int chunk = (E + NBLK - 1) / NBLK; // 6250 edges per bin block

    // ---- workspace layout (16 B aligned chunks) ----
    char* p = (char*)d_ws;
    auto take = [&](size_t bytes) { char* r = p; p += (bytes + 15) & ~(size_t)15; return r; };
    int*      counts = (int*)take(sizeof(int) * NBK * NBLK);
    int*      btot   = (int*)take(sizeof(int) * NBK);
    int*      bucketBase = (int*)take(sizeof(int) * (NBK + 1));
    unsigned* ebuf   = (unsigned*)take(sizeof(unsigned) * E);
    int*      csr    = (int*)take(sizeof(int) * E);
    int*      rowptr = (int*)take(sizeof(int) * (N + 1));
    float*    dinv   = (float*)take(sizeof(float) * N);
    unsigned short* h1b = (unsigned short*)take(sizeof(unsigned short) * (size_t)N * HID);
    float*    h2     = (float*)take(sizeof(float) * (size_t)N * EMB);
    float*    sums   = (float*)take(sizeof(float) * G * EMB);
    float*    cntf   = (float*)take(sizeof(float) * G);
    int*      done   = (int*)take(sizeof(int));

    // 1. fused CSR build (cooperative, 5 phases, zeroes sums/cnt/done)
    {
        int E_ = E, chunk_ = chunk, NBK_ = NBK, N_ = N, nzero_ = 3 * G;
        const int* src_ = src; const int* dst_ = dst;
        void* args[] = { (void*)&src_, (void*)&dst_, (void*)&counts, (void*)&btot,
                         (void*)&bucketBase, (void*)&ebuf, (void*)&rowptr, (void*)&dinv,
                         (void*)&csr, (void*)&sums, (void*)&done,
                         (void*)&E_, (void*)&chunk_, (void*)&NBK_, (void*)&N_, (void*)&nzero_ };
        hipLaunchCooperativeKernel((void*)build_all_kernel, dim3(NBLK), dim3(256),
                                   args, 0, stream);
    }
    // 2. h1' = dinv * (x @ W1)  (MFMA, bf16 out, row-major)
    gemm1_kernel<<<(N + 63) / 64, 256, 0, stream>>>(x, W1, dinv, h1b, N);
    // 3. fused agg1 + relu + W2 -> h2' = dinv * h2
    agg1_layer2_kernel<<<(int)(((long)N * 16 + 255) / 256), 256, 0, stream>>>(
        rowptr, csr, h1b, dinv, b1, W2, h2, N);
    // 4. fused agg2 + pool + finalize
    agg2_pool_final_kernel<<<(N + 255) / 256, 256, 0, stream>>>(
        rowptr, csr, h2, dinv, b2, batch, sums, cntf, out, done, N, G);
}

// Round 9
// 324.554 us; speedup vs baseline: 1.3957x; 1.3957x over previous
//
#include <hip/hip_runtime.h>
#include <hip/hip_bf16.h>

#define FIN 256
#define HID 64
#define EMB 2
#define BKB 9            // bucket = dst >> 9 (512 nodes per bucket)
#define BKSZ 512
#define MAXBK 256        // supports N <= 131072
#define NBLK 256         // blocks for binning passes

typedef __bf16 bf16x8 __attribute__((ext_vector_type(8)));
typedef float  f32x16 __attribute__((ext_vector_type(16)));

// ---- bf16 helpers (RNE) ----
static __device__ __forceinline__ unsigned short f2bf(float f) {
    union { float f; unsigned int u; } v; v.f = f;
    unsigned int u = v.u;
    unsigned int r = (u + 0x7fffu + ((u >> 16) & 1u)) >> 16;
    return (unsigned short)r;
}
static __device__ __forceinline__ float bf2f(unsigned short h) {
    union { unsigned int u; float f; } v; v.u = ((unsigned int)h) << 16;
    return v.f;
}

// ---------------------------------------------------------------------------
// Pass A1: per-block histogram of coarse buckets (dst>>9) -> counts[bucket][block]
__global__ __launch_bounds__(256) void bin_hist_kernel(
        const int* __restrict__ dst, int* __restrict__ counts, int E, int chunk, int NBK) {
    __shared__ int hist[MAXBK];
    int tid = threadIdx.x;
    for (int b = tid; b < NBK; b += 256) hist[b] = 0;
    __syncthreads();
    int e0 = blockIdx.x * chunk, e1 = min(e0 + chunk, E);
    for (int i = e0 + tid; i < e1; i += 256) atomicAdd(&hist[dst[i] >> BKB], 1);
    __syncthreads();
    for (int b = tid; b < NBK; b += 256) counts[b * gridDim.x + blockIdx.x] = hist[b];
}

// Scan 1/2: per-bucket exclusive scan of its 256 per-block counts (in place)
// + bucket total. One block per bucket.
__global__ __launch_bounds__(256) void scan_local_kernel(
        int* __restrict__ counts, int* __restrict__ btot) {
    __shared__ int s[256];
    const int b = blockIdx.x, tid = threadIdx.x;
    int v = counts[b * NBLK + tid];
    s[tid] = v;
    __syncthreads();
    for (int off = 1; off < 256; off <<= 1) {
        int t = (tid >= off) ? s[tid - off] : 0;
        __syncthreads();
        s[tid] += t;
        __syncthreads();
    }
    counts[b * NBLK + tid] = s[tid] - v;   // exclusive within bucket
    if (tid == 255) btot[b] = s[255];
}

// Scan 2/2: single block scans bucket totals -> bucketBase[0..NBK]; also zeroes
// the pool accumulators (sums[G*2] + cntf[G]) and the done flag.
__global__ __launch_bounds__(256) void scan_tot_kernel(
        const int* __restrict__ btot, int* __restrict__ bucketBase,
        float* __restrict__ sums, int* __restrict__ done, int NBK, int nzero) {
    __shared__ int s[256];
    const int tid = threadIdx.x;
    int v = (tid < NBK) ? btot[tid] : 0;
    s[tid] = v;
    __syncthreads();
    for (int off = 1; off < 256; off <<= 1) {
        int t = (tid >= off) ? s[tid - off] : 0;
        __syncthreads();
        s[tid] += t;
        __syncthreads();
    }
    if (tid < NBK) bucketBase[tid] = s[tid] - v;
    if (tid == NBK - 1) bucketBase[NBK] = s[tid];
    for (int i = tid; i < nzero; i += 256) sums[i] = 0.f;
    if (tid == 0) *done = 0;
}

// Pass A2: scatter packed (src<<9 | dst&511) into per-(bucket,block) runs
__global__ __launch_bounds__(256) void bin_scatter_kernel(
        const int* __restrict__ src, const int* __restrict__ dst,
        const int* __restrict__ counts, const int* __restrict__ bucketBase,
        unsigned* __restrict__ ebuf, int E, int chunk, int NBK) {
    __shared__ int cur[MAXBK];
    int tid = threadIdx.x;
    for (int b = tid; b < NBK; b += 256)
        cur[b] = bucketBase[b] + counts[b * gridDim.x + blockIdx.x];
    __syncthreads();
    int e0 = blockIdx.x * chunk, e1 = min(e0 + chunk, E);
    for (int i = e0 + tid; i < e1; i += 256) {
        int s = src[i], d = dst[i];
        int b = d >> BKB;
        int pos = atomicAdd(&cur[b], 1);
        ebuf[pos] = ((unsigned)s << BKB) | (unsigned)(d & (BKSZ - 1));
    }
}

// Pass B: one block per bucket -> degree/dinv/rowptr + bucket-local CSR scatter
__global__ __launch_bounds__(256) void build_kernel(
        const unsigned* __restrict__ ebuf, const int* __restrict__ bucketBase,
        int* __restrict__ rowptr, float* __restrict__ dinv, int* __restrict__ csr,
        int N, int E) {
    __shared__ int hist[BKSZ];
    __shared__ int scanb[256];
    __shared__ int cur[BKSZ];
    const int b = blockIdx.x, tid = threadIdx.x;
    const int r0 = bucketBase[b];
    const int r1 = bucketBase[b + 1];
    const int nb0 = b * BKSZ;

    hist[tid] = 0; hist[tid + 256] = 0;
    __syncthreads();
    for (int i = r0 + tid; i < r1; i += 256)
        atomicAdd(&hist[ebuf[i] & (BKSZ - 1u)], 1);
    __syncthreads();

    int h0 = hist[2 * tid], h1 = hist[2 * tid + 1];
    if (nb0 + 2 * tid < N)     dinv[nb0 + 2 * tid]     = rsqrtf((float)h0 + 1.f);
    if (nb0 + 2 * tid + 1 < N) dinv[nb0 + 2 * tid + 1] = rsqrtf((float)h1 + 1.f);
    scanb[tid] = h0 + h1;
    __syncthreads();
    for (int off = 1; off < 256; off <<= 1) {
        int t = (tid >= off) ? scanb[tid - off] : 0;
        __syncthreads();
        scanb[tid] += t;
        __syncthreads();
    }
    int base0 = scanb[tid] - (h0 + h1);
    int o0 = base0, o1 = base0 + h0;
    cur[2 * tid] = o0; cur[2 * tid + 1] = o1;
    if (nb0 + 2 * tid < N)     rowptr[nb0 + 2 * tid]     = r0 + o0;
    if (nb0 + 2 * tid + 1 < N) rowptr[nb0 + 2 * tid + 1] = r0 + o1;
    if (nb0 + BKSZ >= N && tid == 0) rowptr[N] = E;
    __syncthreads();
    for (int i = r0 + tid; i < r1; i += 256) {
        unsigned u = ebuf[i];
        int loc = (int)(u & (BKSZ - 1u));
        int p = atomicAdd(&cur[loc], 1);
        csr[r0 + p] = (int)(u >> BKB);
    }
}

// ---------------------------------------------------------------------------
// h1' = dinv * (x @ W1) via MFMA (bf16 hi/lo split: xh*wh + xh*wl + xl*wh).
// Block = 64-node x 64-feat tile, 4 waves = four 32x32 quadrants. bf16 store.
__global__ __launch_bounds__(256) void gemm1_kernel(
        const float* __restrict__ x, const float* __restrict__ W,
        const float* __restrict__ dinv, unsigned short* __restrict__ h1b, int N) {
    __shared__ __align__(16) __bf16 A_hi[2 * 4 * 64 * 8];
    __shared__ __align__(16) __bf16 A_lo[2 * 4 * 64 * 8];
    __shared__ __align__(16) __bf16 B_hi[2 * 4 * 64 * 8];
    __shared__ __align__(16) __bf16 B_lo[2 * 4 * 64 * 8];

    const int tid = threadIdx.x;
    const int base = blockIdx.x * 64;
    const int w = tid >> 6;
    const int l = tid & 63;
    const int mg = w >> 1, ng = w & 1;

    f32x16 acc = {};

    const int r  = tid & 63;
    const int ks = tid >> 6;
    const int rl = r & 31, rh = r >> 5;

    for (int ch = 0; ch < 4; ++ch) {
        const int ck0 = ch * 64;
        __syncthreads();
        {
            int row = base + r;
            float f[16];
            if (row < N) {
                const float* xp = &x[(size_t)row * FIN + ck0 + ks * 16];
                float4 v0 = *(const float4*)(xp + 0);
                float4 v1 = *(const float4*)(xp + 4);
                float4 v2 = *(const float4*)(xp + 8);
                float4 v3 = *(const float4*)(xp + 12);
                f[0]=v0.x; f[1]=v0.y; f[2]=v0.z; f[3]=v0.w;
                f[4]=v1.x; f[5]=v1.y; f[6]=v1.z; f[7]=v1.w;
                f[8]=v2.x; f[9]=v2.y; f[10]=v2.z; f[11]=v2.w;
                f[12]=v3.x; f[13]=v3.y; f[14]=v3.z; f[15]=v3.w;
            } else {
                #pragma unroll
                for (int q = 0; q < 16; ++q) f[q] = 0.f;
            }
            bf16x8 ha, hb, la, lb;
            #pragma unroll
            for (int q = 0; q < 8; ++q) {
                __bf16 h0 = (__bf16)f[q];
                ha[q] = h0; la[q] = (__bf16)(f[q] - (float)h0);
                __bf16 h1v = (__bf16)f[q + 8];
                hb[q] = h1v; lb[q] = (__bf16)(f[q + 8] - (float)h1v);
            }
            int ra = ((rh * 4 + ks) * 64 + rl) * 8;
            int rb = ((rh * 4 + ks) * 64 + 32 + rl) * 8;
            *(bf16x8*)&A_hi[ra] = ha; *(bf16x8*)&A_hi[rb] = hb;
            *(bf16x8*)&A_lo[ra] = la; *(bf16x8*)&A_lo[rb] = lb;
        }
        {
            const float* wp = &W[(size_t)(ck0 + ks * 16) * HID + r];
            float f[16];
            #pragma unroll
            for (int q = 0; q < 16; ++q) f[q] = wp[q * HID];
            bf16x8 ha, hb, la, lb;
            #pragma unroll
            for (int q = 0; q < 8; ++q) {
                __bf16 h0 = (__bf16)f[q];
                ha[q] = h0; la[q] = (__bf16)(f[q] - (float)h0);
                __bf16 h1v = (__bf16)f[q + 8];
                hb[q] = h1v; lb[q] = (__bf16)(f[q + 8] - (float)h1v);
            }
            int ra = ((rh * 4 + ks) * 64 + rl) * 8;
            int rb = ((rh * 4 + ks) * 64 + 32 + rl) * 8;
            *(bf16x8*)&B_hi[ra] = ha; *(bf16x8*)&B_hi[rb] = hb;
            *(bf16x8*)&B_lo[ra] = la; *(bf16x8*)&B_lo[rb] = lb;
        }
        __syncthreads();

        #pragma unroll
        for (int s = 0; s < 4; ++s) {
            bf16x8 a_h = *(const bf16x8*)&A_hi[((mg * 4 + s) * 64 + l) * 8];
            bf16x8 a_l = *(const bf16x8*)&A_lo[((mg * 4 + s) * 64 + l) * 8];
            bf16x8 b_h = *(const bf16x8*)&B_hi[((ng * 4 + s) * 64 + l) * 8];
            bf16x8 b_l = *(const bf16x8*)&B_lo[((ng * 4 + s) * 64 + l) * 8];
            acc = __builtin_amdgcn_mfma_f32_32x32x16_bf16(a_h, b_h, acc, 0, 0, 0);
            acc = __builtin_amdgcn_mfma_f32_32x32x16_bf16(a_h, b_l, acc, 0, 0, 0);
            acc = __builtin_amdgcn_mfma_f32_32x32x16_bf16(a_l, b_h, acc, 0, 0, 0);
        }
    }

    const int col = l & 31;
    const int rbase = 4 * (l >> 5);
    #pragma unroll
    for (int reg = 0; reg < 16; ++reg) {
        int row = (reg & 3) + 8 * (reg >> 2) + rbase;
        int node = base + mg * 32 + row;
        if (node < N)
            h1b[(size_t)node * HID + ng * 32 + col] = f2bf(acc[reg] * dinv[node]);
    }
}

// ---------------------------------------------------------------------------
// Fused layer-1 CSR gather (pure sum of pre-scaled h1') + b1 + ReLU + (64->2).
// 4 nodes per wave: 16 lanes/node, lane = 4 feats (ushort4 gather). Unroll 8.
__global__ __launch_bounds__(256) void agg1_layer2_kernel(
        const int* __restrict__ rowptr, const int* __restrict__ csr,
        const unsigned short* __restrict__ h1b,
        const float* __restrict__ dinv, const float* __restrict__ b1,
        const float* __restrict__ W2, float* __restrict__ h2, int N) {
    long t = (long)blockIdx.x * blockDim.x + threadIdx.x;
    int n = (int)(t >> 4);
    int li = threadIdx.x & 15;
    if (n >= N) return;
    const ushort4* h14 = (const ushort4*)h1b;

    float di = dinv[n];
    ushort4 sl = h14[(size_t)n * 16 + li];       // self term (h1' pre-scaled)
    float v0 = bf2f(sl.x), v1 = bf2f(sl.y);
    float v2 = bf2f(sl.z), v3 = bf2f(sl.w);

    int j0 = rowptr[n], j1 = rowptr[n + 1];
    int j = j0;
    for (; j + 7 < j1; j += 8) {
        int s0 = csr[j],     s1 = csr[j + 1], s2 = csr[j + 2], s3 = csr[j + 3];
        int s4 = csr[j + 4], s5 = csr[j + 5], s6 = csr[j + 6], s7 = csr[j + 7];
        ushort4 g0 = h14[(size_t)s0 * 16 + li];
        ushort4 g1 = h14[(size_t)s1 * 16 + li];
        ushort4 g2 = h14[(size_t)s2 * 16 + li];
        ushort4 g3 = h14[(size_t)s3 * 16 + li];
        ushort4 g4 = h14[(size_t)s4 * 16 + li];
        ushort4 g5 = h14[(size_t)s5 * 16 + li];
        ushort4 g6 = h14[(size_t)s6 * 16 + li];
        ushort4 g7 = h14[(size_t)s7 * 16 + li];
        v0 += bf2f(g0.x) + bf2f(g1.x) + bf2f(g2.x) + bf2f(g3.x)
            + bf2f(g4.x) + bf2f(g5.x) + bf2f(g6.x) + bf2f(g7.x);
        v1 += bf2f(g0.y) + bf2f(g1.y) + bf2f(g2.y) + bf2f(g3.y)
            + bf2f(g4.y) + bf2f(g5.y) + bf2f(g6.y) + bf2f(g7.y);
        v2 += bf2f(g0.z) + bf2f(g1.z) + bf2f(g2.z) + bf2f(g3.z)
            + bf2f(g4.z) + bf2f(g5.z) + bf2f(g6.z) + bf2f(g7.z);
        v3 += bf2f(g0.w) + bf2f(g1.w) + bf2f(g2.w) + bf2f(g3.w)
            + bf2f(g4.w) + bf2f(g5.w) + bf2f(g6.w) + bf2f(g7.w);
    }
    for (; j < j1; ++j) {
        int s = csr[j];
        ushort4 g = h14[(size_t)s * 16 + li];
        v0 += bf2f(g.x); v1 += bf2f(g.y); v2 += bf2f(g.z); v3 += bf2f(g.w);
    }

    const float4 b4 = *(const float4*)&b1[li * 4];
    v0 = fmaxf(di * v0 + b4.x, 0.f); v1 = fmaxf(di * v1 + b4.y, 0.f);
    v2 = fmaxf(di * v2 + b4.z, 0.f); v3 = fmaxf(di * v3 + b4.w, 0.f);

    const float4* W24 = (const float4*)W2;
    float4 wa = W24[li * 2], wb = W24[li * 2 + 1];
    float r0 = v0 * wa.x + v1 * wa.z + v2 * wb.x + v3 * wb.z;
    float r1 = v0 * wa.y + v1 * wa.w + v2 * wb.y + v3 * wb.w;
    #pragma unroll
    for (int off = 1; off < 16; off <<= 1) {
        r0 += __shfl_xor(r0, off);
        r1 += __shfl_xor(r1, off);
    }
    if (li == 0) *(float2*)&h2[(size_t)n * EMB] = make_float2(r0 * di, r1 * di);  // h2' = dinv*h2
}

// ---------------------------------------------------------------------------
// Fused layer-2 CSR gather (pure sum of h2') + b2 + global mean pool
// + last-block finalize (sums/cnt -> out).
__global__ __launch_bounds__(256) void agg2_pool_final_kernel(
        const int* __restrict__ rowptr, const int* __restrict__ csr,
        const float* __restrict__ h2,
        const float* __restrict__ dinv, const float* __restrict__ b2,
        const int* __restrict__ batch,
        float* __restrict__ sums, float* __restrict__ cntf,
        float* __restrict__ out, int* __restrict__ done, int N, int G) {
    int n = blockIdx.x * blockDim.x + threadIdx.x;
    int lane = threadIdx.x & 63;
    const float2* h2v = (const float2*)h2;
    float v0 = 0.f, v1 = 0.f, c = 0.f;
    int g = -1;
    if (n < N) {
        float di = dinv[n];
        float2 hs = h2v[n];
        v0 = hs.x; v1 = hs.y;
        int j0 = rowptr[n], j1 = rowptr[n + 1];
        int j = j0;
        for (; j + 3 < j1; j += 4) {
            int s0 = csr[j], s1 = csr[j + 1], s2 = csr[j + 2], s3 = csr[j + 3];
            float2 a = h2v[s0], b = h2v[s1], cc = h2v[s2], d = h2v[s3];
            v0 += a.x + b.x + cc.x + d.x;
            v1 += a.y + b.y + cc.y + d.y;
        }
        for (; j < j1; ++j) {
            float2 hv = h2v[csr[j]];
            v0 += hv.x; v1 += hv.y;
        }
        v0 = di * v0 + b2[0];
        v1 = di * v1 + b2[1];
        g = batch[n];
        c = 1.f;
    }
    #pragma unroll
    for (int off = 1; off < 64; off <<= 1) {
        int gg = __shfl_up(g, off);
        float t0 = __shfl_up(v0, off);
        float t1 = __shfl_up(v1, off);
        float tc = __shfl_up(c, off);
        if (lane >= off && gg == g) { v0 += t0; v1 += t1; c += tc; }
    }
    int gn = __shfl_down(g, 1);
    if (g >= 0 && (lane == 63 || gn != g)) {
        atomicAdd(&sums[g * EMB + 0], v0);
        atomicAdd(&sums[g * EMB + 1], v1);
        atomicAdd(&cntf[g], c);
    }

    // last-finished block finalizes out = sums / max(cnt,1)
    __shared__ int isLast;
    __threadfence();
    if (threadIdx.x == 0) {
        int v = atomicAdd(done, 1);
        isLast = (v == (int)gridDim.x - 1);
    }
    __syncthreads();
    if (isLast) {
        __threadfence();
        const volatile float* vs = sums;
        const volatile float* vc = cntf;
        for (int gg = threadIdx.x; gg < G; gg += blockDim.x) {
            float cc = vc[gg];
            cc = fmaxf(cc, 1.0f);
            out[gg * EMB + 0] = vs[gg * EMB + 0] / cc;
            out[gg * EMB + 1] = vs[gg * EMB + 1] / cc;
        }
    }
}

// ---------------------------------------------------------------------------
extern "C" void kernel_launch(void* const* d_in, const int* in_sizes, int n_in,
                              void* d_out, int out_size, void* d_ws, size_t ws_size,
                              hipStream_t stream) {
    const float* x     = (const float*)d_in[0];
    const int*   ei    = (const int*)d_in[1];
    const int*   batch = (const int*)d_in[2];
    const float* W1    = (const float*)d_in[3];
    const float* b1    = (const float*)d_in[4];
    const float* W2    = (const float*)d_in[5];
    const float* b2    = (const float*)d_in[6];
    float* out = (float*)d_out;

    const int N = in_sizes[0] / FIN;   // 100000
    const int E = in_sizes[1] / 2;     // 1600000
    const int G = out_size / EMB;      // 512
    const int* src = ei;
    const int* dst = ei + E;

    const int NBK = (N + BKSZ - 1) / BKSZ;   // 196 coarse buckets
    const int chunk = (E + NBLK - 1) / NBLK; // 6250 edges per bin block

    // ---- workspace layout (16 B aligned chunks) ----
    char* p = (char*)d_ws;
    auto take = [&](size_t bytes) { char* r = p; p += (bytes + 15) & ~(size_t)15; return r; };
    int*      counts = (int*)take(sizeof(int) * NBK * NBLK);
    int*      btot   = (int*)take(sizeof(int) * NBK);
    int*      bucketBase = (int*)take(sizeof(int) * (NBK + 1));
    unsigned* ebuf   = (unsigned*)take(sizeof(unsigned) * E);
    int*      csr    = (int*)take(sizeof(int) * E);
    int*      rowptr = (int*)take(sizeof(int) * (N + 1));
    float*    dinv   = (float*)take(sizeof(float) * N);
    unsigned short* h1b = (unsigned short*)take(sizeof(unsigned short) * (size_t)N * HID);
    float*    h2     = (float*)take(sizeof(float) * (size_t)N * EMB);
    float*    sums   = (float*)take(sizeof(float) * G * EMB);
    float*    cntf   = (float*)take(sizeof(float) * G);
    int*      done   = (int*)take(sizeof(int));

    // 1. CSR build: hist -> 2-level bucket scan (+zero sums/done) -> scatter -> build
    bin_hist_kernel<<<NBLK, 256, 0, stream>>>(dst, counts, E, chunk, NBK);
    scan_local_kernel<<<NBK, 256, 0, stream>>>(counts, btot);
    scan_tot_kernel<<<1, 256, 0, stream>>>(btot, bucketBase, sums, done, NBK, 3 * G);
    bin_scatter_kernel<<<NBLK, 256, 0, stream>>>(src, dst, counts, bucketBase, ebuf, E, chunk, NBK);
    build_kernel<<<NBK, 256, 0, stream>>>(ebuf, bucketBase, rowptr, dinv, csr, N, E);
    // 2. h1' = dinv * (x @ W1)  (MFMA, bf16 out, row-major)
    gemm1_kernel<<<(N + 63) / 64, 256, 0, stream>>>(x, W1, dinv, h1b, N);
    // 3. fused agg1 + relu + W2 -> h2' = dinv * h2
    agg1_layer2_kernel<<<(int)(((long)N * 16 + 255) / 256), 256, 0, stream>>>(
        rowptr, csr, h1b, dinv, b1, W2, h2, N);
    // 4. fused agg2 + pool + finalize
    agg2_pool_final_kernel<<<(N + 255) / 256, 256, 0, stream>>>(
        rowptr, csr, h2, dinv, b2, batch, sums, cntf, out, done, N, G);
}

// Round 10
// 291.642 us; speedup vs baseline: 1.5532x; 1.1129x over previous
//
#include <hip/hip_runtime.h>
#include <hip/hip_bf16.h>

#define FIN 256
#define HID 64
#define EMB 2
#define BKB 9            // bucket = dst >> 9 (512 nodes per bucket)
#define BKSZ 512
#define MAXBK 256        // supports N <= 131072
#define NBLK 256         // blocks for binning passes

typedef __bf16 bf16x8 __attribute__((ext_vector_type(8)));
typedef float  f32x16 __attribute__((ext_vector_type(16)));

// ---- bf16 helpers (RNE) ----
static __device__ __forceinline__ unsigned short f2bf(float f) {
    union { float f; unsigned int u; } v; v.f = f;
    unsigned int u = v.u;
    unsigned int r = (u + 0x7fffu + ((u >> 16) & 1u)) >> 16;
    return (unsigned short)r;
}
static __device__ __forceinline__ float bf2f(unsigned short h) {
    union { unsigned int u; float f; } v; v.u = ((unsigned int)h) << 16;
    return v.f;
}

// ---------------------------------------------------------------------------
// Pass A1: per-block histogram of coarse buckets (dst>>9) -> counts[bucket][block]
// int4 vector loads (chunk is a multiple of 4 -> each block slice is 16B-aligned).
__global__ __launch_bounds__(256) void bin_hist_kernel(
        const int* __restrict__ dst, int* __restrict__ counts, int E, int chunk, int NBK) {
    __shared__ int hist[MAXBK];
    int tid = threadIdx.x;
    for (int b = tid; b < NBK; b += 256) hist[b] = 0;
    __syncthreads();
    int e0 = blockIdx.x * chunk, e1 = min(e0 + chunk, E);
    if (e0 < e1) {
        const int4* d4 = (const int4*)(dst + e0);
        int nv = (e1 - e0) >> 2;
        for (int i = tid; i < nv; i += 256) {
            int4 v = d4[i];
            atomicAdd(&hist[v.x >> BKB], 1);
            atomicAdd(&hist[v.y >> BKB], 1);
            atomicAdd(&hist[v.z >> BKB], 1);
            atomicAdd(&hist[v.w >> BKB], 1);
        }
        for (int i = e0 + (nv << 2) + tid; i < e1; i += 256)
            atomicAdd(&hist[dst[i] >> BKB], 1);
    }
    __syncthreads();
    for (int b = tid; b < NBK; b += 256) counts[b * gridDim.x + blockIdx.x] = hist[b];
}

// Scan 1/2: per-bucket exclusive scan of its 256 per-block counts (in place)
// + bucket total. One block per bucket.
__global__ __launch_bounds__(256) void scan_local_kernel(
        int* __restrict__ counts, int* __restrict__ btot) {
    __shared__ int s[256];
    const int b = blockIdx.x, tid = threadIdx.x;
    int v = counts[b * NBLK + tid];
    s[tid] = v;
    __syncthreads();
    for (int off = 1; off < 256; off <<= 1) {
        int t = (tid >= off) ? s[tid - off] : 0;
        __syncthreads();
        s[tid] += t;
        __syncthreads();
    }
    counts[b * NBLK + tid] = s[tid] - v;   // exclusive within bucket
    if (tid == 255) btot[b] = s[255];
}

// Scan 2/2: single block scans bucket totals -> bucketBase[0..NBK]; also zeroes
// the pool accumulators (sums[G*2] + cntf[G]).
__global__ __launch_bounds__(256) void scan_tot_kernel(
        const int* __restrict__ btot, int* __restrict__ bucketBase,
        float* __restrict__ sums, int NBK, int nzero) {
    __shared__ int s[256];
    const int tid = threadIdx.x;
    int v = (tid < NBK) ? btot[tid] : 0;
    s[tid] = v;
    __syncthreads();
    for (int off = 1; off < 256; off <<= 1) {
        int t = (tid >= off) ? s[tid - off] : 0;
        __syncthreads();
        s[tid] += t;
        __syncthreads();
    }
    if (tid < NBK) bucketBase[tid] = s[tid] - v;
    if (tid == NBK - 1) bucketBase[NBK] = s[tid];
    for (int i = tid; i < nzero; i += 256) sums[i] = 0.f;
}

// Pass A2: scatter packed (src<<9 | dst&511) into per-(bucket,block) runs.
// int4 vector loads of src/dst (same chunking as bin_hist -> counts match).
__global__ __launch_bounds__(256) void bin_scatter_kernel(
        const int* __restrict__ src, const int* __restrict__ dst,
        const int* __restrict__ counts, const int* __restrict__ bucketBase,
        unsigned* __restrict__ ebuf, int E, int chunk, int NBK) {
    __shared__ int cur[MAXBK];
    int tid = threadIdx.x;
    for (int b = tid; b < NBK; b += 256)
        cur[b] = bucketBase[b] + counts[b * gridDim.x + blockIdx.x];
    __syncthreads();
    int e0 = blockIdx.x * chunk, e1 = min(e0 + chunk, E);
    if (e0 >= e1) return;
    const int4* s4 = (const int4*)(src + e0);
    const int4* d4 = (const int4*)(dst + e0);
    int nv = (e1 - e0) >> 2;
    for (int i = tid; i < nv; i += 256) {
        int4 sv = s4[i], dv = d4[i];
        int b0 = dv.x >> BKB;
        int p0 = atomicAdd(&cur[b0], 1);
        ebuf[p0] = ((unsigned)sv.x << BKB) | (unsigned)(dv.x & (BKSZ - 1));
        int b1 = dv.y >> BKB;
        int p1 = atomicAdd(&cur[b1], 1);
        ebuf[p1] = ((unsigned)sv.y << BKB) | (unsigned)(dv.y & (BKSZ - 1));
        int b2 = dv.z >> BKB;
        int p2 = atomicAdd(&cur[b2], 1);
        ebuf[p2] = ((unsigned)sv.z << BKB) | (unsigned)(dv.z & (BKSZ - 1));
        int b3 = dv.w >> BKB;
        int p3 = atomicAdd(&cur[b3], 1);
        ebuf[p3] = ((unsigned)sv.w << BKB) | (unsigned)(dv.w & (BKSZ - 1));
    }
    for (int i = e0 + (nv << 2) + tid; i < e1; i += 256) {
        int s = src[i], d = dst[i];
        int b = d >> BKB;
        int pos = atomicAdd(&cur[b], 1);
        ebuf[pos] = ((unsigned)s << BKB) | (unsigned)(d & (BKSZ - 1));
    }
}

// Pass B: one block per bucket -> degree/dinv/rowptr + bucket-local CSR scatter
__global__ __launch_bounds__(256) void build_kernel(
        const unsigned* __restrict__ ebuf, const int* __restrict__ bucketBase,
        int* __restrict__ rowptr, float* __restrict__ dinv, int* __restrict__ csr,
        int N, int E) {
    __shared__ int hist[BKSZ];
    __shared__ int scanb[256];
    __shared__ int cur[BKSZ];
    const int b = blockIdx.x, tid = threadIdx.x;
    const int r0 = bucketBase[b];
    const int r1 = bucketBase[b + 1];
    const int nb0 = b * BKSZ;

    hist[tid] = 0; hist[tid + 256] = 0;
    __syncthreads();
    for (int i = r0 + tid; i < r1; i += 256)
        atomicAdd(&hist[ebuf[i] & (BKSZ - 1u)], 1);
    __syncthreads();

    int h0 = hist[2 * tid], h1 = hist[2 * tid + 1];
    if (nb0 + 2 * tid < N)     dinv[nb0 + 2 * tid]     = rsqrtf((float)h0 + 1.f);
    if (nb0 + 2 * tid + 1 < N) dinv[nb0 + 2 * tid + 1] = rsqrtf((float)h1 + 1.f);
    scanb[tid] = h0 + h1;
    __syncthreads();
    for (int off = 1; off < 256; off <<= 1) {
        int t = (tid >= off) ? scanb[tid - off] : 0;
        __syncthreads();
        scanb[tid] += t;
        __syncthreads();
    }
    int base0 = scanb[tid] - (h0 + h1);
    int o0 = base0, o1 = base0 + h0;
    cur[2 * tid] = o0; cur[2 * tid + 1] = o1;
    if (nb0 + 2 * tid < N)     rowptr[nb0 + 2 * tid]     = r0 + o0;
    if (nb0 + 2 * tid + 1 < N) rowptr[nb0 + 2 * tid + 1] = r0 + o1;
    if (nb0 + BKSZ >= N && tid == 0) rowptr[N] = E;
    __syncthreads();
    for (int i = r0 + tid; i < r1; i += 256) {
        unsigned u = ebuf[i];
        int loc = (int)(u & (BKSZ - 1u));
        int p = atomicAdd(&cur[loc], 1);
        csr[r0 + p] = (int)(u >> BKB);
    }
}

// ---------------------------------------------------------------------------
// h1' = dinv * (x @ W1) via MFMA (bf16 hi/lo split: xh*wh + xh*wl + xl*wh).
// Block = 64-node x 64-feat tile, 4 waves = four 32x32 quadrants. bf16 store.
__global__ __launch_bounds__(256) void gemm1_kernel(
        const float* __restrict__ x, const float* __restrict__ W,
        const float* __restrict__ dinv, unsigned short* __restrict__ h1b, int N) {
    __shared__ __align__(16) __bf16 A_hi[2 * 4 * 64 * 8];
    __shared__ __align__(16) __bf16 A_lo[2 * 4 * 64 * 8];
    __shared__ __align__(16) __bf16 B_hi[2 * 4 * 64 * 8];
    __shared__ __align__(16) __bf16 B_lo[2 * 4 * 64 * 8];

    const int tid = threadIdx.x;
    const int base = blockIdx.x * 64;
    const int w = tid >> 6;
    const int l = tid & 63;
    const int mg = w >> 1, ng = w & 1;

    f32x16 acc = {};

    const int r  = tid & 63;
    const int ks = tid >> 6;
    const int rl = r & 31, rh = r >> 5;

    for (int ch = 0; ch < 4; ++ch) {
        const int ck0 = ch * 64;
        __syncthreads();
        {
            int row = base + r;
            float f[16];
            if (row < N) {
                const float* xp = &x[(size_t)row * FIN + ck0 + ks * 16];
                float4 v0 = *(const float4*)(xp + 0);
                float4 v1 = *(const float4*)(xp + 4);
                float4 v2 = *(const float4*)(xp + 8);
                float4 v3 = *(const float4*)(xp + 12);
                f[0]=v0.x; f[1]=v0.y; f[2]=v0.z; f[3]=v0.w;
                f[4]=v1.x; f[5]=v1.y; f[6]=v1.z; f[7]=v1.w;
                f[8]=v2.x; f[9]=v2.y; f[10]=v2.z; f[11]=v2.w;
                f[12]=v3.x; f[13]=v3.y; f[14]=v3.z; f[15]=v3.w;
            } else {
                #pragma unroll
                for (int q = 0; q < 16; ++q) f[q] = 0.f;
            }
            bf16x8 ha, hb, la, lb;
            #pragma unroll
            for (int q = 0; q < 8; ++q) {
                __bf16 h0 = (__bf16)f[q];
                ha[q] = h0; la[q] = (__bf16)(f[q] - (float)h0);
                __bf16 h1v = (__bf16)f[q + 8];
                hb[q] = h1v; lb[q] = (__bf16)(f[q + 8] - (float)h1v);
            }
            int ra = ((rh * 4 + ks) * 64 + rl) * 8;
            int rb = ((rh * 4 + ks) * 64 + 32 + rl) * 8;
            *(bf16x8*)&A_hi[ra] = ha; *(bf16x8*)&A_hi[rb] = hb;
            *(bf16x8*)&A_lo[ra] = la; *(bf16x8*)&A_lo[rb] = lb;
        }
        {
            const float* wp = &W[(size_t)(ck0 + ks * 16) * HID + r];
            float f[16];
            #pragma unroll
            for (int q = 0; q < 16; ++q) f[q] = wp[q * HID];
            bf16x8 ha, hb, la, lb;
            #pragma unroll
            for (int q = 0; q < 8; ++q) {
                __bf16 h0 = (__bf16)f[q];
                ha[q] = h0; la[q] = (__bf16)(f[q] - (float)h0);
                __bf16 h1v = (__bf16)f[q + 8];
                hb[q] = h1v; lb[q] = (__bf16)(f[q + 8] - (float)h1v);
            }
            int ra = ((rh * 4 + ks) * 64 + rl) * 8;
            int rb = ((rh * 4 + ks) * 64 + 32 + rl) * 8;
            *(bf16x8*)&B_hi[ra] = ha; *(bf16x8*)&B_hi[rb] = hb;
            *(bf16x8*)&B_lo[ra] = la; *(bf16x8*)&B_lo[rb] = lb;
        }
        __syncthreads();

        #pragma unroll
        for (int s = 0; s < 4; ++s) {
            bf16x8 a_h = *(const bf16x8*)&A_hi[((mg * 4 + s) * 64 + l) * 8];
            bf16x8 a_l = *(const bf16x8*)&A_lo[((mg * 4 + s) * 64 + l) * 8];
            bf16x8 b_h = *(const bf16x8*)&B_hi[((ng * 4 + s) * 64 + l) * 8];
            bf16x8 b_l = *(const bf16x8*)&B_lo[((ng * 4 + s) * 64 + l) * 8];
            acc = __builtin_amdgcn_mfma_f32_32x32x16_bf16(a_h, b_h, acc, 0, 0, 0);
            acc = __builtin_amdgcn_mfma_f32_32x32x16_bf16(a_h, b_l, acc, 0, 0, 0);
            acc = __builtin_amdgcn_mfma_f32_32x32x16_bf16(a_l, b_h, acc, 0, 0, 0);
        }
    }

    const int col = l & 31;
    const int rbase = 4 * (l >> 5);
    #pragma unroll
    for (int reg = 0; reg < 16; ++reg) {
        int row = (reg & 3) + 8 * (reg >> 2) + rbase;
        int node = base + mg * 32 + row;
        if (node < N)
            h1b[(size_t)node * HID + ng * 32 + col] = f2bf(acc[reg] * dinv[node]);
    }
}

// ---------------------------------------------------------------------------
// Fused layer-1 CSR gather (pure sum of pre-scaled h1') + b1 + ReLU + (64->2).
// 4 nodes per wave: 16 lanes/node, lane = 4 feats (ushort4 gather). Unroll 4
// (unroll-8 regressed in R9: longer scalar tail at avg degree 16).
__global__ __launch_bounds__(256) void agg1_layer2_kernel(
        const int* __restrict__ rowptr, const int* __restrict__ csr,
        const unsigned short* __restrict__ h1b,
        const float* __restrict__ dinv, const float* __restrict__ b1,
        const float* __restrict__ W2, float* __restrict__ h2, int N) {
    long t = (long)blockIdx.x * blockDim.x + threadIdx.x;
    int n = (int)(t >> 4);
    int li = threadIdx.x & 15;
    if (n >= N) return;
    const ushort4* h14 = (const ushort4*)h1b;

    float di = dinv[n];
    ushort4 sl = h14[(size_t)n * 16 + li];       // self term (h1' pre-scaled)
    float v0 = bf2f(sl.x), v1 = bf2f(sl.y);
    float v2 = bf2f(sl.z), v3 = bf2f(sl.w);

    int j0 = rowptr[n], j1 = rowptr[n + 1];
    int j = j0;
    for (; j + 3 < j1; j += 4) {
        int s0 = csr[j], s1 = csr[j + 1], s2 = csr[j + 2], s3 = csr[j + 3];
        ushort4 g0 = h14[(size_t)s0 * 16 + li];
        ushort4 g1 = h14[(size_t)s1 * 16 + li];
        ushort4 g2 = h14[(size_t)s2 * 16 + li];
        ushort4 g3 = h14[(size_t)s3 * 16 + li];
        v0 += bf2f(g0.x) + bf2f(g1.x) + bf2f(g2.x) + bf2f(g3.x);
        v1 += bf2f(g0.y) + bf2f(g1.y) + bf2f(g2.y) + bf2f(g3.y);
        v2 += bf2f(g0.z) + bf2f(g1.z) + bf2f(g2.z) + bf2f(g3.z);
        v3 += bf2f(g0.w) + bf2f(g1.w) + bf2f(g2.w) + bf2f(g3.w);
    }
    for (; j < j1; ++j) {
        int s = csr[j];
        ushort4 g = h14[(size_t)s * 16 + li];
        v0 += bf2f(g.x); v1 += bf2f(g.y); v2 += bf2f(g.z); v3 += bf2f(g.w);
    }

    const float4 b4 = *(const float4*)&b1[li * 4];
    v0 = fmaxf(di * v0 + b4.x, 0.f); v1 = fmaxf(di * v1 + b4.y, 0.f);
    v2 = fmaxf(di * v2 + b4.z, 0.f); v3 = fmaxf(di * v3 + b4.w, 0.f);

    const float4* W24 = (const float4*)W2;
    float4 wa = W24[li * 2], wb = W24[li * 2 + 1];
    float r0 = v0 * wa.x + v1 * wa.z + v2 * wb.x + v3 * wb.z;
    float r1 = v0 * wa.y + v1 * wa.w + v2 * wb.y + v3 * wb.w;
    #pragma unroll
    for (int off = 1; off < 16; off <<= 1) {
        r0 += __shfl_xor(r0, off);
        r1 += __shfl_xor(r1, off);
    }
    if (li == 0) *(float2*)&h2[(size_t)n * EMB] = make_float2(r0 * di, r1 * di);  // h2' = dinv*h2
}

// ---------------------------------------------------------------------------
// Fused layer-2 CSR gather (pure sum of h2') + b2 + global mean pool.
__global__ __launch_bounds__(256) void agg2_pool_kernel(
        const int* __restrict__ rowptr, const int* __restrict__ csr,
        const float* __restrict__ h2,
        const float* __restrict__ dinv, const float* __restrict__ b2,
        const int* __restrict__ batch,
        float* __restrict__ sums, float* __restrict__ cntf, int N) {
    int n = blockIdx.x * blockDim.x + threadIdx.x;
    int lane = threadIdx.x & 63;
    const float2* h2v = (const float2*)h2;
    float v0 = 0.f, v1 = 0.f, c = 0.f;
    int g = -1;
    if (n < N) {
        float di = dinv[n];
        float2 hs = h2v[n];
        v0 = hs.x; v1 = hs.y;
        int j0 = rowptr[n], j1 = rowptr[n + 1];
        int j = j0;
        for (; j + 3 < j1; j += 4) {
            int s0 = csr[j], s1 = csr[j + 1], s2 = csr[j + 2], s3 = csr[j + 3];
            float2 a = h2v[s0], b = h2v[s1], cc = h2v[s2], d = h2v[s3];
            v0 += a.x + b.x + cc.x + d.x;
            v1 += a.y + b.y + cc.y + d.y;
        }
        for (; j < j1; ++j) {
            float2 hv = h2v[csr[j]];
            v0 += hv.x; v1 += hv.y;
        }
        v0 = di * v0 + b2[0];
        v1 = di * v1 + b2[1];
        g = batch[n];
        c = 1.f;
    }
    #pragma unroll
    for (int off = 1; off < 64; off <<= 1) {
        int gg = __shfl_up(g, off);
        float t0 = __shfl_up(v0, off);
        float t1 = __shfl_up(v1, off);
        float tc = __shfl_up(c, off);
        if (lane >= off && gg == g) { v0 += t0; v1 += t1; c += tc; }
    }
    int gn = __shfl_down(g, 1);
    if (g >= 0 && (lane == 63 || gn != g)) {
        atomicAdd(&sums[g * EMB + 0], v0);
        atomicAdd(&sums[g * EMB + 1], v1);
        atomicAdd(&cntf[g], c);
    }
}

__global__ void final_kernel(const float* __restrict__ sums, const float* __restrict__ cntf,
                             float* __restrict__ out, int G) {
    int g = blockIdx.x * blockDim.x + threadIdx.x;
    if (g >= G) return;
    float c = fmaxf(cntf[g], 1.0f);
    out[g * EMB + 0] = sums[g * EMB + 0] / c;
    out[g * EMB + 1] = sums[g * EMB + 1] / c;
}

// ---------------------------------------------------------------------------
extern "C" void kernel_launch(void* const* d_in, const int* in_sizes, int n_in,
                              void* d_out, int out_size, void* d_ws, size_t ws_size,
                              hipStream_t stream) {
    const float* x     = (const float*)d_in[0];
    const int*   ei    = (const int*)d_in[1];
    const int*   batch = (const int*)d_in[2];
    const float* W1    = (const float*)d_in[3];
    const float* b1    = (const float*)d_in[4];
    const float* W2    = (const float*)d_in[5];
    const float* b2    = (const float*)d_in[6];
    float* out = (float*)d_out;

    const int N = in_sizes[0] / FIN;   // 100000
    const int E = in_sizes[1] / 2;     // 1600000
    const int G = out_size / EMB;      // 512
    const int* src = ei;
    const int* dst = ei + E;

    const int NBK = (N + BKSZ - 1) / BKSZ;                    // 196 coarse buckets
    const int chunk = (((E + NBLK - 1) / NBLK) + 3) & ~3;     // x4 -> 16B-aligned slices

    // ---- workspace layout (16 B aligned chunks) ----
    char* p = (char*)d_ws;
    auto take = [&](size_t bytes) { char* r = p; p += (bytes + 15) & ~(size_t)15; return r; };
    int*      counts = (int*)take(sizeof(int) * NBK * NBLK);
    int*      btot   = (int*)take(sizeof(int) * NBK);
    int*      bucketBase = (int*)take(sizeof(int) * (NBK + 1));
    unsigned* ebuf   = (unsigned*)take(sizeof(unsigned) * E);
    int*      csr    = (int*)take(sizeof(int) * E);
    int*      rowptr = (int*)take(sizeof(int) * (N + 1));
    float*    dinv   = (float*)take(sizeof(float) * N);
    unsigned short* h1b = (unsigned short*)take(sizeof(unsigned short) * (size_t)N * HID);
    float*    h2     = (float*)take(sizeof(float) * (size_t)N * EMB);
    float*    sums   = (float*)take(sizeof(float) * G * EMB);
    float*    cntf   = (float*)take(sizeof(float) * G);

    // 1. CSR build: hist -> 2-level bucket scan (+zero sums) -> scatter -> build
    bin_hist_kernel<<<NBLK, 256, 0, stream>>>(dst, counts, E, chunk, NBK);
    scan_local_kernel<<<NBK, 256, 0, stream>>>(counts, btot);
    scan_tot_kernel<<<1, 256, 0, stream>>>(btot, bucketBase, sums, NBK, 3 * G);
    bin_scatter_kernel<<<NBLK, 256, 0, stream>>>(src, dst, counts, bucketBase, ebuf, E, chunk, NBK);
    build_kernel<<<NBK, 256, 0, stream>>>(ebuf, bucketBase, rowptr, dinv, csr, N, E);
    // 2. h1' = dinv * (x @ W1)  (MFMA, bf16 out, row-major)
    gemm1_kernel<<<(N + 63) / 64, 256, 0, stream>>>(x, W1, dinv, h1b, N);
    // 3. fused agg1 + relu + W2 -> h2' = dinv * h2
    agg1_layer2_kernel<<<(int)(((long)N * 16 + 255) / 256), 256, 0, stream>>>(
        rowptr, csr, h1b, dinv, b1, W2, h2, N);
    // 4. fused agg2 + pool, then finalize
    agg2_pool_kernel<<<(N + 255) / 256, 256, 0, stream>>>(
        rowptr, csr, h2, dinv, b2, batch, sums, cntf, N);
    final_kernel<<<(G + 255) / 256, 256, 0, stream>>>(sums, cntf, out, G);
}

// Round 11
// 290.221 us; speedup vs baseline: 1.5608x; 1.0049x over previous
//
#include <hip/hip_runtime.h>
#include <hip/hip_bf16.h>

#define FIN 256
#define HID 64
#define EMB 2
#define BKB 9            // bucket = dst >> 9 (512 nodes per bucket)
#define BKSZ 512
#define MAXBK 256        // supports N <= 131072
#define NBLK 256         // blocks for binning passes

typedef __bf16 bf16x8 __attribute__((ext_vector_type(8)));
typedef float  f32x16 __attribute__((ext_vector_type(16)));
typedef unsigned short u16x8 __attribute__((ext_vector_type(8)));

// ---- bf16 helpers (RNE) ----
static __device__ __forceinline__ unsigned short f2bf(float f) {
    union { float f; unsigned int u; } v; v.f = f;
    unsigned int u = v.u;
    unsigned int r = (u + 0x7fffu + ((u >> 16) & 1u)) >> 16;
    return (unsigned short)r;
}
static __device__ __forceinline__ float bf2f(unsigned short h) {
    union { unsigned int u; float f; } v; v.u = ((unsigned int)h) << 16;
    return v.f;
}

// ---------------------------------------------------------------------------
// Pass A1: per-block histogram of coarse buckets (dst>>9) -> counts[bucket][block]
// int4 vector loads (chunk is a multiple of 4 -> each block slice is 16B-aligned).
__global__ __launch_bounds__(256) void bin_hist_kernel(
        const int* __restrict__ dst, int* __restrict__ counts, int E, int chunk, int NBK) {
    __shared__ int hist[MAXBK];
    int tid = threadIdx.x;
    for (int b = tid; b < NBK; b += 256) hist[b] = 0;
    __syncthreads();
    int e0 = blockIdx.x * chunk, e1 = min(e0 + chunk, E);
    if (e0 < e1) {
        const int4* d4 = (const int4*)(dst + e0);
        int nv = (e1 - e0) >> 2;
        for (int i = tid; i < nv; i += 256) {
            int4 v = d4[i];
            atomicAdd(&hist[v.x >> BKB], 1);
            atomicAdd(&hist[v.y >> BKB], 1);
            atomicAdd(&hist[v.z >> BKB], 1);
            atomicAdd(&hist[v.w >> BKB], 1);
        }
        for (int i = e0 + (nv << 2) + tid; i < e1; i += 256)
            atomicAdd(&hist[dst[i] >> BKB], 1);
    }
    __syncthreads();
    for (int b = tid; b < NBK; b += 256) counts[b * gridDim.x + blockIdx.x] = hist[b];
}

// Scan 1/2: per-bucket exclusive scan of its 256 per-block counts (in place)
// + bucket total. One block per bucket.
__global__ __launch_bounds__(256) void scan_local_kernel(
        int* __restrict__ counts, int* __restrict__ btot) {
    __shared__ int s[256];
    const int b = blockIdx.x, tid = threadIdx.x;
    int v = counts[b * NBLK + tid];
    s[tid] = v;
    __syncthreads();
    for (int off = 1; off < 256; off <<= 1) {
        int t = (tid >= off) ? s[tid - off] : 0;
        __syncthreads();
        s[tid] += t;
        __syncthreads();
    }
    counts[b * NBLK + tid] = s[tid] - v;   // exclusive within bucket
    if (tid == 255) btot[b] = s[255];
}

// Scan 2/2: single block scans bucket totals -> bucketBase[0..NBK]; also zeroes
// the pool accumulators (sums[G*2] + cntf[G]).
__global__ __launch_bounds__(256) void scan_tot_kernel(
        const int* __restrict__ btot, int* __restrict__ bucketBase,
        float* __restrict__ sums, int NBK, int nzero) {
    __shared__ int s[256];
    const int tid = threadIdx.x;
    int v = (tid < NBK) ? btot[tid] : 0;
    s[tid] = v;
    __syncthreads();
    for (int off = 1; off < 256; off <<= 1) {
        int t = (tid >= off) ? s[tid - off] : 0;
        __syncthreads();
        s[tid] += t;
        __syncthreads();
    }
    if (tid < NBK) bucketBase[tid] = s[tid] - v;
    if (tid == NBK - 1) bucketBase[NBK] = s[tid];
    for (int i = tid; i < nzero; i += 256) sums[i] = 0.f;
}

// Pass A2: scatter packed (src<<9 | dst&511) into per-(bucket,block) runs.
// int4 vector loads of src/dst (same chunking as bin_hist -> counts match).
__global__ __launch_bounds__(256) void bin_scatter_kernel(
        const int* __restrict__ src, const int* __restrict__ dst,
        const int* __restrict__ counts, const int* __restrict__ bucketBase,
        unsigned* __restrict__ ebuf, int E, int chunk, int NBK) {
    __shared__ int cur[MAXBK];
    int tid = threadIdx.x;
    for (int b = tid; b < NBK; b += 256)
        cur[b] = bucketBase[b] + counts[b * gridDim.x + blockIdx.x];
    __syncthreads();
    int e0 = blockIdx.x * chunk, e1 = min(e0 + chunk, E);
    if (e0 >= e1) return;
    const int4* s4 = (const int4*)(src + e0);
    const int4* d4 = (const int4*)(dst + e0);
    int nv = (e1 - e0) >> 2;
    for (int i = tid; i < nv; i += 256) {
        int4 sv = s4[i], dv = d4[i];
        int b0 = dv.x >> BKB;
        int p0 = atomicAdd(&cur[b0], 1);
        ebuf[p0] = ((unsigned)sv.x << BKB) | (unsigned)(dv.x & (BKSZ - 1));
        int b1 = dv.y >> BKB;
        int p1 = atomicAdd(&cur[b1], 1);
        ebuf[p1] = ((unsigned)sv.y << BKB) | (unsigned)(dv.y & (BKSZ - 1));
        int b2 = dv.z >> BKB;
        int p2 = atomicAdd(&cur[b2], 1);
        ebuf[p2] = ((unsigned)sv.z << BKB) | (unsigned)(dv.z & (BKSZ - 1));
        int b3 = dv.w >> BKB;
        int p3 = atomicAdd(&cur[b3], 1);
        ebuf[p3] = ((unsigned)sv.w << BKB) | (unsigned)(dv.w & (BKSZ - 1));
    }
    for (int i = e0 + (nv << 2) + tid; i < e1; i += 256) {
        int s = src[i], d = dst[i];
        int b = d >> BKB;
        int pos = atomicAdd(&cur[b], 1);
        ebuf[pos] = ((unsigned)s << BKB) | (unsigned)(d & (BKSZ - 1));
    }
}

// Pass B: one block per bucket -> degree/dinv/rowptr + bucket-local CSR scatter
__global__ __launch_bounds__(256) void build_kernel(
        const unsigned* __restrict__ ebuf, const int* __restrict__ bucketBase,
        int* __restrict__ rowptr, float* __restrict__ dinv, int* __restrict__ csr,
        int N, int E) {
    __shared__ int hist[BKSZ];
    __shared__ int scanb[256];
    __shared__ int cur[BKSZ];
    const int b = blockIdx.x, tid = threadIdx.x;
    const int r0 = bucketBase[b];
    const int r1 = bucketBase[b + 1];
    const int nb0 = b * BKSZ;

    hist[tid] = 0; hist[tid + 256] = 0;
    __syncthreads();
    for (int i = r0 + tid; i < r1; i += 256)
        atomicAdd(&hist[ebuf[i] & (BKSZ - 1u)], 1);
    __syncthreads();

    int h0 = hist[2 * tid], h1 = hist[2 * tid + 1];
    if (nb0 + 2 * tid < N)     dinv[nb0 + 2 * tid]     = rsqrtf((float)h0 + 1.f);
    if (nb0 + 2 * tid + 1 < N) dinv[nb0 + 2 * tid + 1] = rsqrtf((float)h1 + 1.f);
    scanb[tid] = h0 + h1;
    __syncthreads();
    for (int off = 1; off < 256; off <<= 1) {
        int t = (tid >= off) ? scanb[tid - off] : 0;
        __syncthreads();
        scanb[tid] += t;
        __syncthreads();
    }
    int base0 = scanb[tid] - (h0 + h1);
    int o0 = base0, o1 = base0 + h0;
    cur[2 * tid] = o0; cur[2 * tid + 1] = o1;
    if (nb0 + 2 * tid < N)     rowptr[nb0 + 2 * tid]     = r0 + o0;
    if (nb0 + 2 * tid + 1 < N) rowptr[nb0 + 2 * tid + 1] = r0 + o1;
    if (nb0 + BKSZ >= N && tid == 0) rowptr[N] = E;
    __syncthreads();
    for (int i = r0 + tid; i < r1; i += 256) {
        unsigned u = ebuf[i];
        int loc = (int)(u & (BKSZ - 1u));
        int p = atomicAdd(&cur[loc], 1);
        csr[r0 + p] = (int)(u >> BKB);
    }
}

// ---------------------------------------------------------------------------
// h1' = dinv * (x @ W1) via MFMA (bf16 hi/lo split: xh*wh + xh*wl + xl*wh).
// Block = 64-node x 64-feat tile, 4 waves = four 32x32 quadrants. bf16 store.
__global__ __launch_bounds__(256) void gemm1_kernel(
        const float* __restrict__ x, const float* __restrict__ W,
        const float* __restrict__ dinv, unsigned short* __restrict__ h1b, int N) {
    __shared__ __align__(16) __bf16 A_hi[2 * 4 * 64 * 8];
    __shared__ __align__(16) __bf16 A_lo[2 * 4 * 64 * 8];
    __shared__ __align__(16) __bf16 B_hi[2 * 4 * 64 * 8];
    __shared__ __align__(16) __bf16 B_lo[2 * 4 * 64 * 8];

    const int tid = threadIdx.x;
    const int base = blockIdx.x * 64;
    const int w = tid >> 6;
    const int l = tid & 63;
    const int mg = w >> 1, ng = w & 1;

    f32x16 acc = {};

    const int r  = tid & 63;
    const int ks = tid >> 6;
    const int rl = r & 31, rh = r >> 5;

    for (int ch = 0; ch < 4; ++ch) {
        const int ck0 = ch * 64;
        __syncthreads();
        {
            int row = base + r;
            float f[16];
            if (row < N) {
                const float* xp = &x[(size_t)row * FIN + ck0 + ks * 16];
                float4 v0 = *(const float4*)(xp + 0);
                float4 v1 = *(const float4*)(xp + 4);
                float4 v2 = *(const float4*)(xp + 8);
                float4 v3 = *(const float4*)(xp + 12);
                f[0]=v0.x; f[1]=v0.y; f[2]=v0.z; f[3]=v0.w;
                f[4]=v1.x; f[5]=v1.y; f[6]=v1.z; f[7]=v1.w;
                f[8]=v2.x; f[9]=v2.y; f[10]=v2.z; f[11]=v2.w;
                f[12]=v3.x; f[13]=v3.y; f[14]=v3.z; f[15]=v3.w;
            } else {
                #pragma unroll
                for (int q = 0; q < 16; ++q) f[q] = 0.f;
            }
            bf16x8 ha, hb, la, lb;
            #pragma unroll
            for (int q = 0; q < 8; ++q) {
                __bf16 h0 = (__bf16)f[q];
                ha[q] = h0; la[q] = (__bf16)(f[q] - (float)h0);
                __bf16 h1v = (__bf16)f[q + 8];
                hb[q] = h1v; lb[q] = (__bf16)(f[q + 8] - (float)h1v);
            }
            int ra = ((rh * 4 + ks) * 64 + rl) * 8;
            int rb = ((rh * 4 + ks) * 64 + 32 + rl) * 8;
            *(bf16x8*)&A_hi[ra] = ha; *(bf16x8*)&A_hi[rb] = hb;
            *(bf16x8*)&A_lo[ra] = la; *(bf16x8*)&A_lo[rb] = lb;
        }
        {
            const float* wp = &W[(size_t)(ck0 + ks * 16) * HID + r];
            float f[16];
            #pragma unroll
            for (int q = 0; q < 16; ++q) f[q] = wp[q * HID];
            bf16x8 ha, hb, la, lb;
            #pragma unroll
            for (int q = 0; q < 8; ++q) {
                __bf16 h0 = (__bf16)f[q];
                ha[q] = h0; la[q] = (__bf16)(f[q] - (float)h0);
                __bf16 h1v = (__bf16)f[q + 8];
                hb[q] = h1v; lb[q] = (__bf16)(f[q + 8] - (float)h1v);
            }
            int ra = ((rh * 4 + ks) * 64 + rl) * 8;
            int rb = ((rh * 4 + ks) * 64 + 32 + rl) * 8;
            *(bf16x8*)&B_hi[ra] = ha; *(bf16x8*)&B_hi[rb] = hb;
            *(bf16x8*)&B_lo[ra] = la; *(bf16x8*)&B_lo[rb] = lb;
        }
        __syncthreads();

        #pragma unroll
        for (int s = 0; s < 4; ++s) {
            bf16x8 a_h = *(const bf16x8*)&A_hi[((mg * 4 + s) * 64 + l) * 8];
            bf16x8 a_l = *(const bf16x8*)&A_lo[((mg * 4 + s) * 64 + l) * 8];
            bf16x8 b_h = *(const bf16x8*)&B_hi[((ng * 4 + s) * 64 + l) * 8];
            bf16x8 b_l = *(const bf16x8*)&B_lo[((ng * 4 + s) * 64 + l) * 8];
            acc = __builtin_amdgcn_mfma_f32_32x32x16_bf16(a_h, b_h, acc, 0, 0, 0);
            acc = __builtin_amdgcn_mfma_f32_32x32x16_bf16(a_h, b_l, acc, 0, 0, 0);
            acc = __builtin_amdgcn_mfma_f32_32x32x16_bf16(a_l, b_h, acc, 0, 0, 0);
        }
    }

    const int col = l & 31;
    const int rbase = 4 * (l >> 5);
    #pragma unroll
    for (int reg = 0; reg < 16; ++reg) {
        int row = (reg & 3) + 8 * (reg >> 2) + rbase;
        int node = base + mg * 32 + row;
        if (node < N)
            h1b[(size_t)node * HID + ng * 32 + col] = f2bf(acc[reg] * dinv[node]);
    }
}

// ---------------------------------------------------------------------------
// Fused layer-1 CSR gather (pure sum of pre-scaled h1') + b1 + ReLU + (64->2).
// 8 nodes per wave: 8 lanes/node, lane = 8 feats (ushort8 = 16 B/lane gather ->
// 1 KiB / 8 random lines per wave VMEM instruction, the coalescing sweet spot).
__global__ __launch_bounds__(256) void agg1_layer2_kernel(
        const int* __restrict__ rowptr, const int* __restrict__ csr,
        const unsigned short* __restrict__ h1b,
        const float* __restrict__ dinv, const float* __restrict__ b1,
        const float* __restrict__ W2, float* __restrict__ h2, int N) {
    long t = (long)blockIdx.x * blockDim.x + threadIdx.x;
    int n = (int)(t >> 3);
    int li = threadIdx.x & 7;
    if (n >= N) return;
    const u16x8* h18 = (const u16x8*)h1b;    // row = 8 vectors x 8 feats

    float di = dinv[n];
    u16x8 sl = h18[(size_t)n * 8 + li];      // self term (h1' pre-scaled)
    float v[8];
    #pragma unroll
    for (int k = 0; k < 8; ++k) v[k] = bf2f(sl[k]);

    int j0 = rowptr[n], j1 = rowptr[n + 1];
    int j = j0;
    for (; j + 3 < j1; j += 4) {
        int s0 = csr[j], s1 = csr[j + 1], s2 = csr[j + 2], s3 = csr[j + 3];
        u16x8 g0 = h18[(size_t)s0 * 8 + li];
        u16x8 g1 = h18[(size_t)s1 * 8 + li];
        u16x8 g2 = h18[(size_t)s2 * 8 + li];
        u16x8 g3 = h18[(size_t)s3 * 8 + li];
        #pragma unroll
        for (int k = 0; k < 8; ++k)
            v[k] += bf2f(g0[k]) + bf2f(g1[k]) + bf2f(g2[k]) + bf2f(g3[k]);
    }
    for (; j < j1; ++j) {
        u16x8 g = h18[(size_t)csr[j] * 8 + li];
        #pragma unroll
        for (int k = 0; k < 8; ++k) v[k] += bf2f(g[k]);
    }

    // bias + ReLU (feats f = li*8 + k)
    const float4 ba = *(const float4*)&b1[li * 8];
    const float4 bb = *(const float4*)&b1[li * 8 + 4];
    v[0] = fmaxf(di * v[0] + ba.x, 0.f); v[1] = fmaxf(di * v[1] + ba.y, 0.f);
    v[2] = fmaxf(di * v[2] + ba.z, 0.f); v[3] = fmaxf(di * v[3] + ba.w, 0.f);
    v[4] = fmaxf(di * v[4] + bb.x, 0.f); v[5] = fmaxf(di * v[5] + bb.y, 0.f);
    v[6] = fmaxf(di * v[6] + bb.z, 0.f); v[7] = fmaxf(di * v[7] + bb.w, 0.f);

    // W2 rows li*8 .. li*8+7 (each row = 2 floats): 4 float4 loads
    const float4* W24 = (const float4*)W2;
    float r0 = 0.f, r1 = 0.f;
    #pragma unroll
    for (int k = 0; k < 4; ++k) {
        float4 wq = W24[li * 4 + k];         // rows li*8+2k (x,y), li*8+2k+1 (z,w)
        r0 += v[2 * k] * wq.x + v[2 * k + 1] * wq.z;
        r1 += v[2 * k] * wq.y + v[2 * k + 1] * wq.w;
    }
    #pragma unroll
    for (int off = 1; off < 8; off <<= 1) {
        r0 += __shfl_xor(r0, off);
        r1 += __shfl_xor(r1, off);
    }
    if (li == 0) *(float2*)&h2[(size_t)n * EMB] = make_float2(r0 * di, r1 * di);  // h2' = dinv*h2
}

// ---------------------------------------------------------------------------
// Fused layer-2 CSR gather (pure sum of h2') + b2 + global mean pool.
__global__ __launch_bounds__(256) void agg2_pool_kernel(
        const int* __restrict__ rowptr, const int* __restrict__ csr,
        const float* __restrict__ h2,
        const float* __restrict__ dinv, const float* __restrict__ b2,
        const int* __restrict__ batch,
        float* __restrict__ sums, float* __restrict__ cntf, int N) {
    int n = blockIdx.x * blockDim.x + threadIdx.x;
    int lane = threadIdx.x & 63;
    const float2* h2v = (const float2*)h2;
    float v0 = 0.f, v1 = 0.f, c = 0.f;
    int g = -1;
    if (n < N) {
        float di = dinv[n];
        float2 hs = h2v[n];
        v0 = hs.x; v1 = hs.y;
        int j0 = rowptr[n], j1 = rowptr[n + 1];
        int j = j0;
        for (; j + 3 < j1; j += 4) {
            int s0 = csr[j], s1 = csr[j + 1], s2 = csr[j + 2], s3 = csr[j + 3];
            float2 a = h2v[s0], b = h2v[s1], cc = h2v[s2], d = h2v[s3];
            v0 += a.x + b.x + cc.x + d.x;
            v1 += a.y + b.y + cc.y + d.y;
        }
        for (; j < j1; ++j) {
            float2 hv = h2v[csr[j]];
            v0 += hv.x; v1 += hv.y;
        }
        v0 = di * v0 + b2[0];
        v1 = di * v1 + b2[1];
        g = batch[n];
        c = 1.f;
    }
    #pragma unroll
    for (int off = 1; off < 64; off <<= 1) {
        int gg = __shfl_up(g, off);
        float t0 = __shfl_up(v0, off);
        float t1 = __shfl_up(v1, off);
        float tc = __shfl_up(c, off);
        if (lane >= off && gg == g) { v0 += t0; v1 += t1; c += tc; }
    }
    int gn = __shfl_down(g, 1);
    if (g >= 0 && (lane == 63 || gn != g)) {
        atomicAdd(&sums[g * EMB + 0], v0);
        atomicAdd(&sums[g * EMB + 1], v1);
        atomicAdd(&cntf[g], c);
    }
}

__global__ void final_kernel(const float* __restrict__ sums, const float* __restrict__ cntf,
                             float* __restrict__ out, int G) {
    int g = blockIdx.x * blockDim.x + threadIdx.x;
    if (g >= G) return;
    float c = fmaxf(cntf[g], 1.0f);
    out[g * EMB + 0] = sums[g * EMB + 0] / c;
    out[g * EMB + 1] = sums[g * EMB + 1] / c;
}

// ---------------------------------------------------------------------------
extern "C" void kernel_launch(void* const* d_in, const int* in_sizes, int n_in,
                              void* d_out, int out_size, void* d_ws, size_t ws_size,
                              hipStream_t stream) {
    const float* x     = (const float*)d_in[0];
    const int*   ei    = (const int*)d_in[1];
    const int*   batch = (const int*)d_in[2];
    const float* W1    = (const float*)d_in[3];
    const float* b1    = (const float*)d_in[4];
    const float* W2    = (const float*)d_in[5];
    const float* b2    = (const float*)d_in[6];
    float* out = (float*)d_out;

    const int N = in_sizes[0] / FIN;   // 100000
    const int E = in_sizes[1] / 2;     // 1600000
    const int G = out_size / EMB;      // 512
    const int* src = ei;
    const int* dst = ei + E;

    const int NBK = (N + BKSZ - 1) / BKSZ;                    // 196 coarse buckets
    const int chunk = (((E + NBLK - 1) / NBLK) + 3) & ~3;     // x4 -> 16B-aligned slices

    // ---- workspace layout (16 B aligned chunks) ----
    char* p = (char*)d_ws;
    auto take = [&](size_t bytes) { char* r = p; p += (bytes + 15) & ~(size_t)15; return r; };
    int*      counts = (int*)take(sizeof(int) * NBK * NBLK);
    int*      btot   = (int*)take(sizeof(int) * NBK);
    int*      bucketBase = (int*)take(sizeof(int) * (NBK + 1));
    unsigned* ebuf   = (unsigned*)take(sizeof(unsigned) * E);
    int*      csr    = (int*)take(sizeof(int) * E);
    int*      rowptr = (int*)take(sizeof(int) * (N + 1));
    float*    dinv   = (float*)take(sizeof(float) * N);
    unsigned short* h1b = (unsigned short*)take(sizeof(unsigned short) * (size_t)N * HID);
    float*    h2     = (float*)take(sizeof(float) * (size_t)N * EMB);
    float*    sums   = (float*)take(sizeof(float) * G * EMB);
    float*    cntf   = (float*)take(sizeof(float) * G);

    // 1. CSR build: hist -> 2-level bucket scan (+zero sums) -> scatter -> build
    bin_hist_kernel<<<NBLK, 256, 0, stream>>>(dst, counts, E, chunk, NBK);
    scan_local_kernel<<<NBK, 256, 0, stream>>>(counts, btot);
    scan_tot_kernel<<<1, 256, 0, stream>>>(btot, bucketBase, sums, NBK, 3 * G);
    bin_scatter_kernel<<<NBLK, 256, 0, stream>>>(src, dst, counts, bucketBase, ebuf, E, chunk, NBK);
    build_kernel<<<NBK, 256, 0, stream>>>(ebuf, bucketBase, rowptr, dinv, csr, N, E);
    // 2. h1' = dinv * (x @ W1)  (MFMA, bf16 out, row-major)
    gemm1_kernel<<<(N + 63) / 64, 256, 0, stream>>>(x, W1, dinv, h1b, N);
    // 3. fused agg1 + relu + W2 -> h2' = dinv * h2  (8 nodes/wave, 16 B/lane)
    agg1_layer2_kernel<<<(int)(((long)N * 8 + 255) / 256), 256, 0, stream>>>(
        rowptr, csr, h1b, dinv, b1, W2, h2, N);
    // 4. fused agg2 + pool, then finalize
    agg2_pool_kernel<<<(N + 255) / 256, 256, 0, stream>>>(
        rowptr, csr, h2, dinv, b2, batch, sums, cntf, N);
    final_kernel<<<(G + 255) / 256, 256, 0, stream>>>(sums, cntf, out, G);
}